// Round 3
// baseline (421.620 us; speedup 1.0000x reference)
//
#include <hip/hip_runtime.h>

// LocallyConnected2d: out[b,o,h,w] = sum_{c,k} x[b,c,h+kh-1,w+kw-1] * wgt[o,c,h,w,k]
// B=8 C=32 O=64 H=W=64 K=9 (kh-major). fp32 in / fp32 out, fp32 accumulate.
//
// R1 lesson: per-thread 36B-stride weight loads = ~36 line-requests per vmem instr
// -> TA-serialization bound at 740 GB/s (12% HBM). R2: weights staged through LDS
// with fully-coalesced dwordx4 loads (each (o,c,h) run = 576 contiguous dwords,
// one wave stages 2 runs: 2x b128 + 1x b32 per lane), read back as ds_read_b32 at
// 9-dword lane stride (2-way bank aliasing = free on gfx950).
// - thread = (w=lane, o-pair via wave id), 8 batch accumulators -> weight read 1x, used 8x
// - x staged per-c into LDS as two stride-16 float4 planes (b0-3 / b4-7)
// - 512 blocks (h x o-octet) x 256 thr; LDS double-buffered (49.5 KB/block,
//   2 blocks/CU, 8 waves/CU); register prefetch of c+1; 1 barrier per c-iter.

#define BB 8
#define CC 32
#define OO 64
#define HH 64
#define WW 64
#define KK 9
#define CHW (CC * HH * WW)   // x batch stride  (131072)
#define OHW (HH * WW)        // x channel stride (4096)
#define RUN (WW * KK)        // weight run per (o,c,h): 576 dwords

__global__ __launch_bounds__(256, 2)
void lc2d_kernel(const float* __restrict__ x,
                 const float* __restrict__ wgt,
                 float* __restrict__ out)
{
  const int tid = threadIdx.x;
  const int w   = tid & 63;           // lane = output column
  const int wv  = tid >> 6;           // wave id = osub (wave-uniform)
  const int h   = blockIdx.x & 63;
  const int og  = blockIdx.x >> 6;    // 0..7
  const int o0b = og * 8;             // block's o base (8 o's per block)
  const int o0  = o0b + wv * 2;       // this thread's o-pair: o0, o0+1

  // LDS: x tile [buf][half(b0-3|b4-7)][dh*66 + w'] (float4), weights [buf][ol*576 + w*9 + k]
  __shared__ float4 xs[2][2][198];          // 12672 B
  __shared__ float  ws[2][8 * RUN];         // 36864 B  (total 49536 B/block)

  // ---- x staging coords (threads 0..197 stage one (dh,w') position, all 8 b) ----
  const int p   = tid;
  const int dh  = (p >= 132) ? 2 : ((p >= 66) ? 1 : 0);
  const int wpp = p - dh * 66;
  const int r   = h + dh - 1;
  const int col = wpp - 1;
  const bool sactive = (p < 198);
  const bool svalid  = sactive && (r >= 0) && (r < HH) && (col >= 0) && (col < WW);
  const int xoff0 = r * WW + col;

  float acc[2][8];
#pragma unroll
  for (int j = 0; j < 2; ++j)
#pragma unroll
    for (int b = 0; b < 8; ++b) acc[j][b] = 0.f;

  // ---- x stage: load to regs (issue early), commit to LDS later ----
  auto load_x = [&](int c, float4& lo, float4& hi) {
    lo = make_float4(0.f, 0.f, 0.f, 0.f);
    hi = make_float4(0.f, 0.f, 0.f, 0.f);
    if (svalid) {
      const float* q = x + (xoff0 + c * OHW);
      lo.x = q[0 * CHW]; lo.y = q[1 * CHW]; lo.z = q[2 * CHW]; lo.w = q[3 * CHW];
      hi.x = q[4 * CHW]; hi.y = q[5 * CHW]; hi.z = q[6 * CHW]; hi.w = q[7 * CHW];
    }
  };
  auto commit_x = [&](int buf, const float4& lo, const float4& hi) {
    if (sactive) { xs[buf][0][p] = lo; xs[buf][1][p] = hi; }
  };

  // ---- weight stage: wave wv stages runs ol = 2wv, 2wv+1 fully coalesced ----
  // run (o,c,h) starts at dword ((o*CC + c)*HH + h) * RUN; 576 dwords = 64 lanes *
  // (float4 + float4 + float). 16B-aligned (run start multiple of 2304 B).
  auto load_w = [&](int c, float4 (&va)[2], float4 (&vb)[2], float (&vc)[2]) {
#pragma unroll
    for (int jr = 0; jr < 2; ++jr) {
      const int ol = wv * 2 + jr;
      const float* g = wgt + (size_t)(((o0b + ol) * CC + c) * HH + h) * RUN;
      va[jr] = *(const float4*)(g + 4 * w);
      vb[jr] = *(const float4*)(g + 256 + 4 * w);
      vc[jr] = g[512 + w];
    }
  };
  auto commit_w = [&](int buf, const float4 (&va)[2], const float4 (&vb)[2],
                      const float (&vc)[2]) {
#pragma unroll
    for (int jr = 0; jr < 2; ++jr) {
      float* l = &ws[buf][(wv * 2 + jr) * RUN];
      *(float4*)(l + 4 * w) = va[jr];
      *(float4*)(l + 256 + 4 * w) = vb[jr];
      l[512 + w] = vc[jr];
    }
  };

  auto compute = [&](int cur) {
    // weights for this thread: 9 consecutive dwords per o, lane stride 9 dwords
    // -> ds_read_b32, 2 lanes/bank (free)
    float wr[2][KK];
#pragma unroll
    for (int j = 0; j < 2; ++j)
#pragma unroll
      for (int k = 0; k < KK; ++k)
        wr[j][k] = ws[cur][(wv * 2 + j) * RUN + w * KK + k];

    float4 plo[KK], phi[KK];
#pragma unroll
    for (int d = 0; d < 3; ++d)
#pragma unroll
      for (int e = 0; e < 3; ++e) {
        plo[d * 3 + e] = xs[cur][0][d * 66 + w + e];
        phi[d * 3 + e] = xs[cur][1][d * 66 + w + e];
      }
#pragma unroll
    for (int k = 0; k < KK; ++k) {
      float xf[8];
      xf[0] = plo[k].x; xf[1] = plo[k].y; xf[2] = plo[k].z; xf[3] = plo[k].w;
      xf[4] = phi[k].x; xf[5] = phi[k].y; xf[6] = phi[k].z; xf[7] = phi[k].w;
#pragma unroll
      for (int j = 0; j < 2; ++j) {
        const float wf = wr[j][k];
#pragma unroll
        for (int b = 0; b < 8; ++b)
          acc[j][b] = fmaf(wf, xf[b], acc[j][b]);
      }
    }
  };

  // ---- prologue ----
  float4 xlo, xhi, wa[2], wb[2];
  float  wc2[2];
  load_x(0, xlo, xhi);
  load_w(0, wa, wb, wc2);
  commit_x(0, xlo, xhi);
  commit_w(0, wa, wb, wc2);
  __syncthreads();

  // ---- main loop: prefetch c+1 to regs, compute c, commit, barrier ----
  for (int c = 0; c < CC - 1; ++c) {
    load_x(c + 1, xlo, xhi);
    load_w(c + 1, wa, wb, wc2);
    compute(c & 1);
    commit_x((c + 1) & 1, xlo, xhi);
    commit_w((c + 1) & 1, wa, wb, wc2);
    __syncthreads();
  }
  compute((CC - 1) & 1);

  // ---- epilogue: out[b,o,h,w], lane-consecutive in w ----
#pragma unroll
  for (int j = 0; j < 2; ++j) {
    const int o = o0 + j;
#pragma unroll
    for (int b = 0; b < 8; ++b)
      out[((b * OO + o) * HH + h) * WW + w] = acc[j][b];
  }
}

extern "C" void kernel_launch(void* const* d_in, const int* in_sizes, int n_in,
                              void* d_out, int out_size, void* d_ws, size_t ws_size,
                              hipStream_t stream) {
  const float* x   = (const float*)d_in[0];
  const float* wgt = (const float*)d_in[1];
  float* out       = (float*)d_out;
  (void)in_sizes; (void)n_in; (void)out_size; (void)d_ws; (void)ws_size;
  lc2d_kernel<<<dim3(HH * (OO / 8)), dim3(256), 0, stream>>>(x, wgt, out);
}